// Round 2
// baseline (1835.939 us; speedup 1.0000x reference)
//
#include <hip/hip_runtime.h>
#include <hip/hip_bf16.h>

#define DM 1024            // d_model
#define DN 4096            // d_neuron
#define BB 2               // batch
#define TT 4096            // seq
#define MR (BB*TT)         // 8192 total GEMM rows
#define TC 1024            // time chunk
#define NTC (TT/TC)        // 4 time chunks
#define CR (BB*TC)         // 2048 rows per chunk
#define CN ((size_t)CR*DN) // per-chunk activation elems
#define SCH 128            // scan sub-chunk
#define NSC (TC/SCH)       // 8 sub-chunks per time chunk

typedef unsigned short u16;
typedef __attribute__((ext_vector_type(8))) short bf16x8;
typedef __attribute__((ext_vector_type(4))) float f32x4;

__device__ __forceinline__ float bf2f(u16 u) {
    unsigned int x = ((unsigned int)u) << 16; float f; __builtin_memcpy(&f, &x, 4); return f;
}
__device__ __forceinline__ u16 f2bf(float f) {
    __hip_bfloat16 h = __float2bfloat16(f); u16 u; __builtin_memcpy(&u, &h, 2); return u;
}
// load 8 consecutive fp32, convert to bf16, pack as int4 (16 B)
__device__ __forceinline__ int4 load8_cvt(const float* __restrict__ p) {
    float4 a = *(const float4*)p;
    float4 b = *(const float4*)(p + 4);
    union { u16 h[8]; int4 v; } u;
    u.h[0]=f2bf(a.x); u.h[1]=f2bf(a.y); u.h[2]=f2bf(a.z); u.h[3]=f2bf(a.w);
    u.h[4]=f2bf(b.x); u.h[5]=f2bf(b.y); u.h[6]=f2bf(b.z); u.h[7]=f2bf(b.w);
    return u.v;
}

#define BM 128
#define BN 128
#define BK 64
#define LDK (BK + 8)   // 72 elems = 144 B rows: 16B-aligned, bank period 8

// ---------------- 4 input projections for one time chunk, fused activations ----------------
// C[lr][n] = sum_k x[grow(lr)][k] * W[n][k];  lr in [0,2048), grow = b*4096 + ci*1024 + tau
__global__ __launch_bounds__(256, 2) void gemm4_kernel(
    const float* __restrict__ X,
    const float* __restrict__ W0, const float* __restrict__ W1,
    const float* __restrict__ W2, const float* __restrict__ W3,
    u16* __restrict__ raw_o, u16* __restrict__ sig_o,
    u16* __restrict__ modp_o, u16* __restrict__ omd_o,
    const float* __restrict__ A_log, const float* __restrict__ b_delta, int ci)
{
    const int w = blockIdx.z;
    const float* Wp = (w == 0) ? W0 : (w == 1) ? W1 : (w == 2) ? W2 : W3;
    u16* Op = (w == 0) ? raw_o : (w == 1) ? sig_o : (w == 2) ? modp_o : omd_o;
    const int n0 = blockIdx.x * BN;
    const int m0 = blockIdx.y * BM;   // local chunk row base, [0,2048)

    alignas(16) __shared__ u16 As[BM * LDK];
    alignas(16) __shared__ u16 Bs[BN * LDK];

    const int tid = threadIdx.x;
    const int lane = tid & 63;
    const int wave = tid >> 6;
    const int wm = (wave >> 1) * 64;
    const int wn = (wave & 1) * 64;
    const int l16 = lane & 15;
    const int quad = lane >> 4;

    const f32x4 z4 = {0.f, 0.f, 0.f, 0.f};
    f32x4 acc[4][4];
#pragma unroll
    for (int i = 0; i < 4; i++)
#pragma unroll
        for (int j = 0; j < 4; j++) acc[i][j] = z4;

    for (int kt = 0; kt < DM; kt += BK) {
        __syncthreads();
#pragma unroll
        for (int it = 0; it < 4; ++it) {
            int idx = it * 256 + tid;
            int r = idx >> 3;
            int c = idx & 7;
            int lr = m0 + r;                                   // local row
            int xrow = ((lr >> 10) << 12) + ci * TC + (lr & 1023); // b*4096+ci*1024+tau
            int4 va = load8_cvt(X + (size_t)xrow * DM + kt + c * 8);
            int4 vb = load8_cvt(Wp + (size_t)(n0 + r) * DM + kt + c * 8);
            *(int4*)(As + r * LDK + c * 8) = va;
            *(int4*)(Bs + r * LDK + c * 8) = vb;
        }
        __syncthreads();
#pragma unroll
        for (int ks = 0; ks < BK; ks += 32) {
            bf16x8 af[4], bfr[4];
#pragma unroll
            for (int i = 0; i < 4; i++)
                af[i] = *(const bf16x8*)(As + (wm + i * 16 + l16) * LDK + ks + quad * 8);
#pragma unroll
            for (int j = 0; j < 4; j++)
                bfr[j] = *(const bf16x8*)(Bs + (wn + j * 16 + l16) * LDK + ks + quad * 8);
#pragma unroll
            for (int i = 0; i < 4; i++)
#pragma unroll
                for (int j = 0; j < 4; j++)
                    acc[i][j] = __builtin_amdgcn_mfma_f32_16x16x32_bf16(af[i], bfr[j], acc[i][j], 0, 0, 0);
        }
    }

    // epilogue: C/D layout col=lane&15, row=quad*4+reg (m89-verified)
#pragma unroll
    for (int i = 0; i < 4; i++) {
#pragma unroll
        for (int j = 0; j < 4; j++) {
            int n = n0 + wn + j * 16 + l16;
            float al = 0.f, bd = 0.f;
            if (w == 3) { al = A_log[n]; bd = b_delta[n]; }
#pragma unroll
            for (int r = 0; r < 4; r++) {
                int m = m0 + wm + i * 16 + quad * 4 + r;   // local chunk row
                float z = acc[i][j][r];
                float o;
                if (w == 0) {
                    o = z;                                   // raw
                } else if (w == 1) {
                    o = 1.f / (1.f + __expf(-z));            // sigmoid gate
                } else if (w == 2) {
                    o = 1.f + tanhf(z);                      // 1 + mod
                } else {
                    float sp = log1pf(__expf(z + bd));       // softplus(z + b_delta)
                    o = -expm1f(-__expf(al) * sp);           // 1 - decay
                }
                Op[(size_t)m * DN + n] = f2bf(o);
            }
        }
    }
}

// ---------------- output GEMM: out[m][dm] = sum_k Z[m][k]*W_out[dm][k], K=4096 ----------------
__global__ __launch_bounds__(256, 2) void gemm_out_kernel(
    const u16* __restrict__ Zb, const float* __restrict__ Wout, float* __restrict__ Out)
{
    const int n0 = blockIdx.x * BN;   // output d_model cols
    const int m0 = blockIdx.y * BM;

    alignas(16) __shared__ u16 As[BM * LDK];
    alignas(16) __shared__ u16 Bs[BN * LDK];

    const int tid = threadIdx.x;
    const int lane = tid & 63;
    const int wave = tid >> 6;
    const int wm = (wave >> 1) * 64;
    const int wn = (wave & 1) * 64;
    const int l16 = lane & 15;
    const int quad = lane >> 4;

    const f32x4 z4 = {0.f, 0.f, 0.f, 0.f};
    f32x4 acc[4][4];
#pragma unroll
    for (int i = 0; i < 4; i++)
#pragma unroll
        for (int j = 0; j < 4; j++) acc[i][j] = z4;

    for (int kt = 0; kt < DN; kt += BK) {
        __syncthreads();
#pragma unroll
        for (int it = 0; it < 4; ++it) {
            int idx = it * 256 + tid;
            int r = idx >> 3;
            int c = idx & 7;
            int4 va = *(const int4*)(Zb + (size_t)(m0 + r) * DN + kt + c * 8);
            int4 vb = load8_cvt(Wout + (size_t)(n0 + r) * DN + kt + c * 8);
            *(int4*)(As + r * LDK + c * 8) = va;
            *(int4*)(Bs + r * LDK + c * 8) = vb;
        }
        __syncthreads();
#pragma unroll
        for (int ks = 0; ks < BK; ks += 32) {
            bf16x8 af[4], bfr[4];
#pragma unroll
            for (int i = 0; i < 4; i++)
                af[i] = *(const bf16x8*)(As + (wm + i * 16 + l16) * LDK + ks + quad * 8);
#pragma unroll
            for (int j = 0; j < 4; j++)
                bfr[j] = *(const bf16x8*)(Bs + (wn + j * 16 + l16) * LDK + ks + quad * 8);
#pragma unroll
            for (int i = 0; i < 4; i++)
#pragma unroll
                for (int j = 0; j < 4; j++)
                    acc[i][j] = __builtin_amdgcn_mfma_f32_16x16x32_bf16(af[i], bfr[j], acc[i][j], 0, 0, 0);
        }
    }

#pragma unroll
    for (int i = 0; i < 4; i++)
#pragma unroll
        for (int j = 0; j < 4; j++) {
            int n = n0 + wn + j * 16 + l16;
#pragma unroll
            for (int r = 0; r < 4; r++) {
                int m = m0 + wm + i * 16 + quad * 4 + r;
                Out[(size_t)m * DM + n] = acc[i][j][r];
            }
        }
}

// ---------------- scan pass 1: per-sub-chunk decay product + partial state (one time chunk) ----
__global__ void scan_pass1(const u16* __restrict__ omd_a, const u16* __restrict__ sig_a,
                           const u16* __restrict__ raw_a,
                           float* __restrict__ Dc, float* __restrict__ Sc)
{
    int tid = threadIdx.x;
    int bx = blockIdx.x;              // 2*8*16 = 256 blocks
    int nb = bx & 15;
    int sc = (bx >> 4) & 7;
    int b = bx >> 7;
    int n = nb * 256 + tid;
    size_t base = ((size_t)(b * TC + sc * SCH)) * DN + n;    // local chunk rows
    float D = 1.f, s = 0.f;
    for (int t = 0; t < SCH; t++) {
        size_t idx = base + (size_t)t * DN;
        float omd = bf2f(omd_a[idx]);
        float sg = bf2f(sig_a[idx]);
        float rw = bf2f(raw_a[idx]);
        float d = 1.f - omd;
        float u = omd * sg * tanhf(rw);
        D *= d;
        s = d * s + u;
    }
    int ci = (b * NSC + sc) * DN + n;
    Dc[ci] = D;
    Sc[ci] = s;
}

// ---------------- scan pass 2: sequential sub-chunk combine; carries state across time chunks --
__global__ void scan_pass2(float* __restrict__ state_cur,
                           const float* __restrict__ Dc, const float* __restrict__ Sc,
                           float* __restrict__ Sinit, float* __restrict__ fs_out)
{
    int tid = threadIdx.x;
    int bx = blockIdx.x;              // 2*16 = 32 blocks
    int nb = bx & 15;
    int b = bx >> 4;
    int n = nb * 256 + tid;
    float s = state_cur[b * DN + n];
    for (int c = 0; c < NSC; c++) {
        int ci = (b * NSC + c) * DN + n;
        Sinit[ci] = s;
        s = Dc[ci] * s + Sc[ci];
    }
    state_cur[b * DN + n] = s;
    fs_out[b * DN + n] = s;           // final chunk's write is the real final_state
}

// ---------------- scan pass 3: re-scan with true init, emit Z (bf16, full array) ----------------
__global__ void scan_pass3(const u16* __restrict__ omd_a, const u16* __restrict__ sig_a,
                           const u16* __restrict__ raw_a, const u16* __restrict__ modp_a,
                           const float* __restrict__ Sinit, const float* __restrict__ sw_logit,
                           u16* __restrict__ Z, int ci_t)
{
    int tid = threadIdx.x;
    int bx = blockIdx.x;              // 256 blocks
    int nb = bx & 15;
    int sc = (bx >> 4) & 7;
    int b = bx >> 7;
    int n = nb * 256 + tid;
    size_t lbase = ((size_t)(b * TC + sc * SCH)) * DN + n;                     // local
    size_t gbase = ((size_t)(b * TT + ci_t * TC + sc * SCH)) * DN + n;         // global Z
    float s = Sinit[(b * NSC + sc) * DN + n];
    float sw = 1.f / (1.f + __expf(-sw_logit[n]));
    float osw = 1.f - sw;
    for (int t = 0; t < SCH; t++) {
        size_t li = lbase + (size_t)t * DN;
        float omd = bf2f(omd_a[li]);
        float sg = bf2f(sig_a[li]);
        float rw = bf2f(raw_a[li]);
        float mp = bf2f(modp_a[li]);
        float d = 1.f - omd;
        float u = omd * sg * tanhf(rw);
        s = d * s + u;
        float g = 0.5f * rw * (1.f + erff(rw * 0.70710678118f));  // exact gelu
        Z[gbase + (size_t)t * DN] = f2bf(mp * (osw * g + sw * s));
    }
}

// ---------------- host launcher ----------------
extern "C" void kernel_launch(void* const* d_in, const int* in_sizes, int n_in,
                              void* d_out, int out_size, void* d_ws, size_t ws_size,
                              hipStream_t stream)
{
    const float* x = (const float*)d_in[0];
    const float* state = (const float*)d_in[1];
    const float* W_main = (const float*)d_in[2];
    const float* W_gate = (const float*)d_in[3];
    const float* W_mod = (const float*)d_in[4];
    const float* W_out = (const float*)d_in[5];
    const float* W_delta = (const float*)d_in[6];
    const float* b_delta = (const float*)d_in[7];
    const float* A_log = (const float*)d_in[8];
    const float* sw_logit = (const float*)d_in[9];

    float* out = (float*)d_out;                       // [B,T,Dm] fp32
    float* fs_out = out + (size_t)MR * DM;            // final_state [B,Dn]

    const size_t NM = (size_t)MR * DN;                // 33.5M
    u16* Zb = (u16*)d_ws;                             // NM u16        (67.1 MB)
    u16* raw_c = Zb + NM;                             // CN u16        (16.8 MB)
    u16* sig_c = raw_c + CN;
    u16* modp_c = sig_c + CN;
    u16* omd_c = modp_c + CN;
    float* Dc = (float*)(omd_c + CN);                 // B*NSC*DN f32  (256 KB)
    float* Sc = Dc + (size_t)BB * NSC * DN;
    float* Sinit = Sc + (size_t)BB * NSC * DN;
    float* state_cur = Sinit + (size_t)BB * NSC * DN; // 8192 f32
    // total ~135 MB

    hipMemcpyAsync(state_cur, state, (size_t)BB * DN * sizeof(float),
                   hipMemcpyDeviceToDevice, stream);

    dim3 gridA(DN / BN, CR / BM, 4);                  // 32 x 16 x 4 per chunk
    for (int ci = 0; ci < NTC; ci++) {
        gemm4_kernel<<<gridA, 256, 0, stream>>>(x, W_main, W_gate, W_mod, W_delta,
                                                raw_c, sig_c, modp_c, omd_c,
                                                A_log, b_delta, ci);
        scan_pass1<<<BB * NSC * (DN / 256), 256, 0, stream>>>(omd_c, sig_c, raw_c, Dc, Sc);
        scan_pass2<<<BB * (DN / 256), 256, 0, stream>>>(state_cur, Dc, Sc, Sinit, fs_out);
        scan_pass3<<<BB * NSC * (DN / 256), 256, 0, stream>>>(omd_c, sig_c, raw_c, modp_c,
                                                              Sinit, sw_logit, Zb, ci);
    }

    dim3 gridB(DM / BN, MR / BM, 1);                  // 8 x 64
    gemm_out_kernel<<<gridB, 256, 0, stream>>>(Zb, W_out, out);
}

// Round 3
// 1277.697 us; speedup vs baseline: 1.4369x; 1.4369x over previous
//
#include <hip/hip_runtime.h>
#include <hip/hip_bf16.h>
#include <stdint.h>

#define DM 1024            // d_model
#define DN 4096            // d_neuron
#define BB 2               // batch
#define TT 4096            // seq
#define MR (BB*TT)         // 8192 total GEMM rows
#define TC 512             // time chunk
#define NTC (TT/TC)        // 8 time chunks
#define CR (BB*TC)         // 1024 rows per chunk
#define CN ((size_t)CR*DN) // per-chunk activation elems (4,194,304)
#define SCH 64             // scan sub-chunk
#define NSC (TC/SCH)       // 8 sub-chunks per time chunk

typedef unsigned short u16;
typedef __attribute__((ext_vector_type(8))) short bf16x8;
typedef __attribute__((ext_vector_type(4))) float f32x4;

__device__ __forceinline__ float bf2f(u16 u) {
    unsigned int x = ((unsigned int)u) << 16; float f; __builtin_memcpy(&f, &x, 4); return f;
}
__device__ __forceinline__ u16 f2bf(float f) {
    __hip_bfloat16 h = __float2bfloat16(f); u16 u; __builtin_memcpy(&u, &h, 2); return u;
}
// load 8 consecutive fp32, convert to bf16, pack as int4 (16 B)
__device__ __forceinline__ int4 load8_cvt(const float* __restrict__ p) {
    float4 a = *(const float4*)p;
    float4 b = *(const float4*)(p + 4);
    union { u16 h[8]; int4 v; } u;
    u.h[0]=f2bf(a.x); u.h[1]=f2bf(a.y); u.h[2]=f2bf(a.z); u.h[3]=f2bf(a.w);
    u.h[4]=f2bf(b.x); u.h[5]=f2bf(b.y); u.h[6]=f2bf(b.z); u.h[7]=f2bf(b.w);
    return u.v;
}
// async global->LDS, 16 B per lane. LDS dest = wave-uniform base + lane*16 (m104/m108).
// generic->AS3 via uintptr truncation (LLVM lowers flat->local addrspacecast the same way).
__device__ __forceinline__ void async16(const void* g, void* l) {
    __builtin_amdgcn_global_load_lds(
        (const __attribute__((address_space(1))) void*)(uintptr_t)g,
        (__attribute__((address_space(3))) void*)(uint32_t)(uintptr_t)l,
        16, 0, 0);
}

// ---------------- fp32 -> bf16 conversion ----------------
__global__ void cvt_kernel(const float4* __restrict__ src, ushort4* __restrict__ dst, int n4) {
    int i = blockIdx.x * 256 + threadIdx.x;
    if (i < n4) {
        float4 v = src[i];
        ushort4 o;
        o.x = f2bf(v.x); o.y = f2bf(v.y); o.z = f2bf(v.z); o.w = f2bf(v.w);
        dst[i] = o;
    }
}

#define BM 128
#define BN 128
#define BK 64
#define PADK (BK + 8)   // padded row for manual-staged operand (tier-2)

// ---------------- 4 input projections for one time chunk, fused activations ----------------
// C[lr][n] = sum_k x[grow(lr)][k] * W[n][k]; lr in [0,CR), grow = b*4096 + ci*TC + tau
template<bool ASYNC_A>
__global__ __launch_bounds__(256, 2) void gemm4_kernel(
    const void* __restrict__ Xsrc,          // bf16 if ASYNC_A else fp32, [8192][1024]
    const u16* __restrict__ W4b,            // bf16 [4][4096][1024]
    u16* __restrict__ raw_o, u16* __restrict__ sig_o,
    u16* __restrict__ modp_o, u16* __restrict__ omd_o,
    const float* __restrict__ A_log, const float* __restrict__ b_delta, int ci)
{
    constexpr int LDA = ASYNC_A ? BK : PADK;
    const int w = blockIdx.z;
    const u16* Wp = W4b + (size_t)w * DN * DM;
    u16* Op = (w == 0) ? raw_o : (w == 1) ? sig_o : (w == 2) ? modp_o : omd_o;
    const int n0 = blockIdx.x * BN;
    const int m0 = blockIdx.y * BM;

    alignas(16) __shared__ u16 As[BM * LDA];
    alignas(16) __shared__ u16 Bs[BN * BK];

    const int tid = threadIdx.x;
    const int lane = tid & 63;
    const int wave = tid >> 6;
    const int wm = (wave >> 1) * 64;
    const int wn = (wave & 1) * 64;
    const int l16 = lane & 15;
    const int quad = lane >> 4;
    const int sr8 = lane >> 3;      // staging: row within group of 8
    const int cl = lane & 7;        // staging: 16B chunk within row

    const f32x4 z4 = {0.f, 0.f, 0.f, 0.f};
    f32x4 acc[4][4];
#pragma unroll
    for (int i = 0; i < 4; i++)
#pragma unroll
        for (int j = 0; j < 4; j++) acc[i][j] = z4;

    for (int kt = 0; kt < DM; kt += BK) {
        __syncthreads();
#pragma unroll
        for (int it = 0; it < 4; ++it) {
            const int r = wave * 32 + it * 8 + sr8;       // tile-local row
            const int cg = cl ^ (r & 7);                  // XOR-8 swizzled global chunk
            async16(Wp + (size_t)(n0 + r) * DM + kt + cg * 8,
                    Bs + (wave * 32 + it * 8) * BK);
            const int lr = m0 + r;
            const int xrow = ((lr >> 9) << 12) + ci * TC + (lr & (TC - 1));
            if constexpr (ASYNC_A) {
                async16((const u16*)Xsrc + (size_t)xrow * DM + kt + cg * 8,
                        As + (wave * 32 + it * 8) * BK);
            } else {
                int4 v = load8_cvt((const float*)Xsrc + (size_t)xrow * DM + kt + cl * 8);
                *(int4*)(As + r * LDA + cl * 8) = v;
            }
        }
        __syncthreads();
#pragma unroll
        for (int ks = 0; ks < BK; ks += 32) {
            bf16x8 af[4], bfr[4];
#pragma unroll
            for (int i = 0; i < 4; i++) {
                const int r = wm + i * 16 + l16;
                const int q = (ks >> 3) + quad;
                const int ch = ASYNC_A ? (q ^ (r & 7)) : q;
                af[i] = *(const bf16x8*)(As + r * LDA + ch * 8);
            }
#pragma unroll
            for (int j = 0; j < 4; j++) {
                const int r = wn + j * 16 + l16;
                const int ch = ((ks >> 3) + quad) ^ (r & 7);
                bfr[j] = *(const bf16x8*)(Bs + r * BK + ch * 8);
            }
#pragma unroll
            for (int i = 0; i < 4; i++)
#pragma unroll
                for (int j = 0; j < 4; j++)
                    acc[i][j] = __builtin_amdgcn_mfma_f32_16x16x32_bf16(af[i], bfr[j], acc[i][j], 0, 0, 0);
        }
    }

    // epilogue: C/D layout col=lane&15, row=quad*4+reg (m89-verified)
#pragma unroll
    for (int i = 0; i < 4; i++) {
#pragma unroll
        for (int j = 0; j < 4; j++) {
            int n = n0 + wn + j * 16 + l16;
            float al = 0.f, bd = 0.f;
            if (w == 3) { al = A_log[n]; bd = b_delta[n]; }
#pragma unroll
            for (int r = 0; r < 4; r++) {
                int m = m0 + wm + i * 16 + quad * 4 + r;   // chunk-local row
                float z = acc[i][j][r];
                float o;
                if (w == 0) {
                    o = z;                                   // raw
                } else if (w == 1) {
                    o = 1.f / (1.f + __expf(-z));            // sigmoid gate
                } else if (w == 2) {
                    o = 1.f + tanhf(z);                      // 1 + mod
                } else {
                    float sp = log1pf(__expf(z + bd));       // softplus(z + b_delta)
                    o = -expm1f(-__expf(al) * sp);           // 1 - decay
                }
                Op[(size_t)m * DN + n] = f2bf(o);
            }
        }
    }
}

// ---------------- output GEMM: out[m][dm] = sum_k Z[m][k]*W_out[dm][k], K=4096 ----------------
template<bool ASYNC_B>
__global__ __launch_bounds__(256, 2) void gemm_out_kernel(
    const u16* __restrict__ Zb, const void* __restrict__ Wsrc, float* __restrict__ Out)
{
    constexpr int LDB = ASYNC_B ? BK : PADK;
    const int n0 = blockIdx.x * BN;   // d_model cols
    const int m0 = blockIdx.y * BM;

    alignas(16) __shared__ u16 As[BM * BK];
    alignas(16) __shared__ u16 Bs[BN * LDB];

    const int tid = threadIdx.x;
    const int lane = tid & 63;
    const int wave = tid >> 6;
    const int wm = (wave >> 1) * 64;
    const int wn = (wave & 1) * 64;
    const int l16 = lane & 15;
    const int quad = lane >> 4;
    const int sr8 = lane >> 3;
    const int cl = lane & 7;

    const f32x4 z4 = {0.f, 0.f, 0.f, 0.f};
    f32x4 acc[4][4];
#pragma unroll
    for (int i = 0; i < 4; i++)
#pragma unroll
        for (int j = 0; j < 4; j++) acc[i][j] = z4;

    for (int kt = 0; kt < DN; kt += BK) {
        __syncthreads();
#pragma unroll
        for (int it = 0; it < 4; ++it) {
            const int r = wave * 32 + it * 8 + sr8;
            const int cg = cl ^ (r & 7);
            async16(Zb + (size_t)(m0 + r) * DN + kt + cg * 8,
                    As + (wave * 32 + it * 8) * BK);
            if constexpr (ASYNC_B) {
                async16((const u16*)Wsrc + (size_t)(n0 + r) * DN + kt + cg * 8,
                        Bs + (wave * 32 + it * 8) * BK);
            } else {
                int4 v = load8_cvt((const float*)Wsrc + (size_t)(n0 + r) * DN + kt + cl * 8);
                *(int4*)(Bs + r * LDB + cl * 8) = v;
            }
        }
        __syncthreads();
#pragma unroll
        for (int ks = 0; ks < BK; ks += 32) {
            bf16x8 af[4], bfr[4];
#pragma unroll
            for (int i = 0; i < 4; i++) {
                const int r = wm + i * 16 + l16;
                const int ch = ((ks >> 3) + quad) ^ (r & 7);
                af[i] = *(const bf16x8*)(As + r * BK + ch * 8);
            }
#pragma unroll
            for (int j = 0; j < 4; j++) {
                const int r = wn + j * 16 + l16;
                const int q = (ks >> 3) + quad;
                const int ch = ASYNC_B ? (q ^ (r & 7)) : q;
                bfr[j] = *(const bf16x8*)(Bs + r * LDB + ch * 8);
            }
#pragma unroll
            for (int i = 0; i < 4; i++)
#pragma unroll
                for (int j = 0; j < 4; j++)
                    acc[i][j] = __builtin_amdgcn_mfma_f32_16x16x32_bf16(af[i], bfr[j], acc[i][j], 0, 0, 0);
        }
    }

#pragma unroll
    for (int i = 0; i < 4; i++)
#pragma unroll
        for (int j = 0; j < 4; j++) {
            int n = n0 + wn + j * 16 + l16;
#pragma unroll
            for (int r = 0; r < 4; r++) {
                int m = m0 + wm + i * 16 + quad * 4 + r;
                Out[(size_t)m * DM + n] = acc[i][j][r];
            }
        }
}

// ---------------- scan pass 1: per-sub-chunk decay product + partial state ----------------
__global__ void scan_pass1(const u16* __restrict__ omd_a, const u16* __restrict__ sig_a,
                           const u16* __restrict__ raw_a,
                           float* __restrict__ Dc, float* __restrict__ Sc)
{
    int tid = threadIdx.x;
    int bx = blockIdx.x;              // BB*NSC*16 = 256 blocks
    int nb = bx & 15;
    int sc = (bx >> 4) & (NSC - 1);
    int b = bx >> 7;
    int n = nb * 256 + tid;
    size_t base = ((size_t)(b * TC + sc * SCH)) * DN + n;
    float D = 1.f, s = 0.f;
    for (int t = 0; t < SCH; t++) {
        size_t idx = base + (size_t)t * DN;
        float omd = bf2f(omd_a[idx]);
        float sg = bf2f(sig_a[idx]);
        float rw = bf2f(raw_a[idx]);
        float d = 1.f - omd;
        float u = omd * sg * tanhf(rw);
        D *= d;
        s = d * s + u;
    }
    int ci = (b * NSC + sc) * DN + n;
    Dc[ci] = D;
    Sc[ci] = s;
}

// ---------------- scan pass 2: sequential sub-chunk combine, carries across time chunks ----
__global__ void scan_pass2(float* __restrict__ state_cur,
                           const float* __restrict__ Dc, const float* __restrict__ Sc,
                           float* __restrict__ Sinit, float* __restrict__ fs_out)
{
    int tid = threadIdx.x;
    int bx = blockIdx.x;              // 32 blocks
    int nb = bx & 15;
    int b = bx >> 4;
    int n = nb * 256 + tid;
    float s = state_cur[b * DN + n];
    for (int c = 0; c < NSC; c++) {
        int ci = (b * NSC + c) * DN + n;
        Sinit[ci] = s;
        s = Dc[ci] * s + Sc[ci];
    }
    state_cur[b * DN + n] = s;
    fs_out[b * DN + n] = s;           // final chunk's write is the real final_state
}

// ---------------- scan pass 3: re-scan with true init, emit Z (bf16, full array) ----------------
__global__ void scan_pass3(const u16* __restrict__ omd_a, const u16* __restrict__ sig_a,
                           const u16* __restrict__ raw_a, const u16* __restrict__ modp_a,
                           const float* __restrict__ Sinit, const float* __restrict__ sw_logit,
                           u16* __restrict__ Z, int ci_t)
{
    int tid = threadIdx.x;
    int bx = blockIdx.x;              // 256 blocks
    int nb = bx & 15;
    int sc = (bx >> 4) & (NSC - 1);
    int b = bx >> 7;
    int n = nb * 256 + tid;
    size_t lbase = ((size_t)(b * TC + sc * SCH)) * DN + n;
    size_t gbase = ((size_t)(b * TT + ci_t * TC + sc * SCH)) * DN + n;
    float s = Sinit[(b * NSC + sc) * DN + n];
    float sw = 1.f / (1.f + __expf(-sw_logit[n]));
    float osw = 1.f - sw;
    for (int t = 0; t < SCH; t++) {
        size_t li = lbase + (size_t)t * DN;
        float omd = bf2f(omd_a[li]);
        float sg = bf2f(sig_a[li]);
        float rw = bf2f(raw_a[li]);
        float mp = bf2f(modp_a[li]);
        float d = 1.f - omd;
        float u = omd * sg * tanhf(rw);
        s = d * s + u;
        float g = 0.5f * rw * (1.f + erff(rw * 0.70710678118f));  // exact gelu
        Z[gbase + (size_t)t * DN] = f2bf(mp * (osw * g + sw * s));
    }
}

// ---------------- host launcher ----------------
extern "C" void kernel_launch(void* const* d_in, const int* in_sizes, int n_in,
                              void* d_out, int out_size, void* d_ws, size_t ws_size,
                              hipStream_t stream)
{
    const float* x = (const float*)d_in[0];
    const float* state = (const float*)d_in[1];
    const float* W_main = (const float*)d_in[2];
    const float* W_gate = (const float*)d_in[3];
    const float* W_mod = (const float*)d_in[4];
    const float* W_out = (const float*)d_in[5];
    const float* W_delta = (const float*)d_in[6];
    const float* b_delta = (const float*)d_in[7];
    const float* A_log = (const float*)d_in[8];
    const float* sw_logit = (const float*)d_in[9];

    float* out = (float*)d_out;                       // [B,T,Dm] fp32
    float* fs_out = out + (size_t)MR * DM;            // final_state [B,Dn]

    const size_t NM = (size_t)MR * DN;
    u16* Zb = (u16*)d_ws;                             // 67.1 MB
    u16* raw_c = Zb + NM;                             // 4 x 8.4 MB chunk activations
    u16* sig_c = raw_c + CN;
    u16* modp_c = sig_c + CN;
    u16* omd_c = modp_c + CN;
    u16* W4b = omd_c + CN;                            // bf16 weights, 33.6 MB
    float* Dc = (float*)(W4b + (size_t)4 * DN * DM);
    float* Sc = Dc + (size_t)BB * NSC * DN;
    float* Sinit = Sc + (size_t)BB * NSC * DN;
    float* state_cur = Sinit + (size_t)BB * NSC * DN;
    // ---- everything above = 135,036,928 B (== round-2 proven footprint) ----
    u16* xb = (u16*)(state_cur + (size_t)BB * DN);    // tier-1 extras: +16.8 MB
    u16* woutb = xb + (size_t)MR * DM;                //               +8.4 MB
    size_t need_t1 = (size_t)((char*)(woutb + (size_t)DM * DN) - (char*)d_ws); // 160,202,752
    const bool tier1 = ws_size >= need_t1;

    hipMemcpyAsync(state_cur, state, (size_t)BB * DN * sizeof(float),
                   hipMemcpyDeviceToDevice, stream);

    // bf16 conversions (weights always; x/W_out only if workspace allows)
    const int w4 = (DN * DM) / 4;
    cvt_kernel<<<w4 / 256, 256, 0, stream>>>((const float4*)W_main,  (ushort4*)(W4b + 0 * (size_t)DN * DM), w4);
    cvt_kernel<<<w4 / 256, 256, 0, stream>>>((const float4*)W_gate,  (ushort4*)(W4b + 1 * (size_t)DN * DM), w4);
    cvt_kernel<<<w4 / 256, 256, 0, stream>>>((const float4*)W_mod,   (ushort4*)(W4b + 2 * (size_t)DN * DM), w4);
    cvt_kernel<<<w4 / 256, 256, 0, stream>>>((const float4*)W_delta, (ushort4*)(W4b + 3 * (size_t)DN * DM), w4);
    if (tier1) {
        const int x4 = (MR * DM) / 4;
        cvt_kernel<<<x4 / 256, 256, 0, stream>>>((const float4*)x, (ushort4*)xb, x4);
        cvt_kernel<<<w4 / 256, 256, 0, stream>>>((const float4*)W_out, (ushort4*)woutb, w4);
    }

    dim3 gridA(DN / BN, CR / BM, 4);                  // 32 x 8 x 4
    for (int ci = 0; ci < NTC; ci++) {
        if (tier1)
            gemm4_kernel<true><<<gridA, 256, 0, stream>>>(xb, W4b, raw_c, sig_c, modp_c, omd_c,
                                                          A_log, b_delta, ci);
        else
            gemm4_kernel<false><<<gridA, 256, 0, stream>>>(x, W4b, raw_c, sig_c, modp_c, omd_c,
                                                           A_log, b_delta, ci);
        scan_pass1<<<BB * NSC * 16, 256, 0, stream>>>(omd_c, sig_c, raw_c, Dc, Sc);
        scan_pass2<<<BB * 16, 256, 0, stream>>>(state_cur, Dc, Sc, Sinit, fs_out);
        scan_pass3<<<BB * NSC * 16, 256, 0, stream>>>(omd_c, sig_c, raw_c, modp_c,
                                                      Sinit, sw_logit, Zb, ci);
    }

    dim3 gridB(DM / BN, MR / BM, 1);                  // 8 x 64
    if (tier1)
        gemm_out_kernel<true><<<gridB, 256, 0, stream>>>(Zb, woutb, out);
    else
        gemm_out_kernel<false><<<gridB, 256, 0, stream>>>(Zb, W_out, out);
}

// Round 4
// 986.071 us; speedup vs baseline: 1.8619x; 1.2957x over previous
//
#include <hip/hip_runtime.h>
#include <hip/hip_bf16.h>
#include <stdint.h>

#define DM 1024            // d_model
#define DN 4096            // d_neuron
#define BB 2               // batch
#define TT 4096            // seq
#define MR (BB*TT)         // 8192 total GEMM rows
#define TC 512             // time chunk
#define NTC (TT/TC)        // 8 time chunks
#define CR (BB*TC)         // 1024 rows per chunk
#define CN ((size_t)CR*DN) // per-chunk activation elems (4,194,304)
#define SCH 32             // scan sub-chunk
#define NSC (TC/SCH)       // 16 sub-chunks per time chunk

typedef unsigned short u16;
typedef __attribute__((ext_vector_type(8))) short bf16x8;
typedef __attribute__((ext_vector_type(4))) float f32x4;

__device__ __forceinline__ float bf2f(u16 u) {
    unsigned int x = ((unsigned int)u) << 16; float f; __builtin_memcpy(&f, &x, 4); return f;
}
__device__ __forceinline__ u16 f2bf(float f) {
    __hip_bfloat16 h = __float2bfloat16(f); u16 u; __builtin_memcpy(&u, &h, 2); return u;
}
// fast tanh: 1 - 2/(exp(2x)+1); exact at +-inf, abs err ~1e-7
__device__ __forceinline__ float tanh_fast(float x) {
    float e = __expf(2.f * x);
    return 1.f - 2.f / (e + 1.f);
}
// A&S 7.1.26 erf poly, max abs err 1.5e-7
__device__ __forceinline__ float erf_fast(float x) {
    float ax = fabsf(x);
    float t = 1.f / (1.f + 0.3275911f * ax);
    float y = t * (0.254829592f + t * (-0.284496736f + t * (1.421413741f +
              t * (-1.453152027f + t * 1.061405429f))));
    float r = 1.f - y * __expf(-ax * ax);
    return copysignf(r, x);
}
// async global->LDS, 16 B per lane (dest = wave-uniform base + lane*16)
__device__ __forceinline__ void async16(const void* g, void* l) {
    __builtin_amdgcn_global_load_lds(
        (const __attribute__((address_space(1))) void*)(uintptr_t)g,
        (__attribute__((address_space(3))) void*)(uint32_t)(uintptr_t)l,
        16, 0, 0);
}

// ---------------- fused fp32 -> bf16 conversion: x + 4 projection weights ----------------
__global__ void cvt5_kernel(const float4* __restrict__ x,
                            const float4* __restrict__ w0, const float4* __restrict__ w1,
                            const float4* __restrict__ w2, const float4* __restrict__ w3,
                            ushort4* __restrict__ xb, ushort4* __restrict__ w4b)
{
    const int XQ = (MR * DM) / 4;        // 2,097,152
    const int WQ = (DN * DM) / 4;        // 1,048,576 = 2^20
    int i = blockIdx.x * 256 + threadIdx.x;
    const float4* s; ushort4* d;
    if (i < XQ) { s = x + i; d = xb + i; }
    else {
        int j = i - XQ;
        int seg = j >> 20;
        int off = j & (WQ - 1);
        const float4* ws = (seg == 0) ? w0 : (seg == 1) ? w1 : (seg == 2) ? w2 : w3;
        s = ws + off; d = w4b + j;
    }
    float4 v = *s;
    ushort4 o; o.x = f2bf(v.x); o.y = f2bf(v.y); o.z = f2bf(v.z); o.w = f2bf(v.w);
    *d = o;
}

__global__ void cvt_kernel(const float4* __restrict__ src, ushort4* __restrict__ dst, int n4) {
    int i = blockIdx.x * 256 + threadIdx.x;
    if (i < n4) {
        float4 v = src[i];
        ushort4 o; o.x = f2bf(v.x); o.y = f2bf(v.y); o.z = f2bf(v.z); o.w = f2bf(v.w);
        dst[i] = o;
    }
}

#define BM 128
#define BN 128
#define BK 64

// ---------------- 4 input projections for one time chunk, fused activations ----------------
__global__ __launch_bounds__(256, 4) void gemm4_kernel(
    const u16* __restrict__ Xb,             // bf16 [8192][1024]
    const u16* __restrict__ W4b,            // bf16 [4][4096][1024]
    u16* __restrict__ raw_o, u16* __restrict__ sig_o,
    u16* __restrict__ modp_o, u16* __restrict__ omd_o,
    const float* __restrict__ A_log, const float* __restrict__ b_delta, int ci)
{
    const int w = blockIdx.z;
    const u16* Wp = W4b + (size_t)w * DN * DM;
    u16* Op = (w == 0) ? raw_o : (w == 1) ? sig_o : (w == 2) ? modp_o : omd_o;
    const int n0 = blockIdx.x * BN;
    const int m0 = blockIdx.y * BM;

    alignas(16) __shared__ u16 As[BM * BK];
    alignas(16) __shared__ u16 Bs[BN * BK];

    const int tid = threadIdx.x;
    const int lane = tid & 63;
    const int wave = tid >> 6;
    const int wm = (wave >> 1) * 64;
    const int wn = (wave & 1) * 64;
    const int l16 = lane & 15;
    const int quad = lane >> 4;
    const int sr8 = lane >> 3;
    const int cl = lane & 7;

    const f32x4 z4 = {0.f, 0.f, 0.f, 0.f};
    f32x4 acc[4][4];
#pragma unroll
    for (int i = 0; i < 4; i++)
#pragma unroll
        for (int j = 0; j < 4; j++) acc[i][j] = z4;

    for (int kt = 0; kt < DM; kt += BK) {
        __syncthreads();
#pragma unroll
        for (int it = 0; it < 4; ++it) {
            const int r = wave * 32 + it * 8 + sr8;
            const int cg = cl ^ (r & 7);                  // XOR-8 swizzle
            async16(Wp + (size_t)(n0 + r) * DM + kt + cg * 8,
                    Bs + (wave * 32 + it * 8) * BK);
            const int lr = m0 + r;
            const int xrow = ((lr >> 9) << 12) + ci * TC + (lr & (TC - 1));
            async16(Xb + (size_t)xrow * DM + kt + cg * 8,
                    As + (wave * 32 + it * 8) * BK);
        }
        __syncthreads();
#pragma unroll
        for (int ks = 0; ks < BK; ks += 32) {
            bf16x8 af[4], bfr[4];
#pragma unroll
            for (int i = 0; i < 4; i++) {
                const int r = wm + i * 16 + l16;
                const int ch = ((ks >> 3) + quad) ^ (r & 7);
                af[i] = *(const bf16x8*)(As + r * BK + ch * 8);
            }
#pragma unroll
            for (int j = 0; j < 4; j++) {
                const int r = wn + j * 16 + l16;
                const int ch = ((ks >> 3) + quad) ^ (r & 7);
                bfr[j] = *(const bf16x8*)(Bs + r * BK + ch * 8);
            }
#pragma unroll
            for (int i = 0; i < 4; i++)
#pragma unroll
                for (int j = 0; j < 4; j++)
                    acc[i][j] = __builtin_amdgcn_mfma_f32_16x16x32_bf16(af[i], bfr[j], acc[i][j], 0, 0, 0);
        }
    }

    // epilogue: C/D layout col=lane&15, row=quad*4+reg (m89-verified)
#pragma unroll
    for (int i = 0; i < 4; i++) {
#pragma unroll
        for (int j = 0; j < 4; j++) {
            int n = n0 + wn + j * 16 + l16;
            float A = 0.f, bd = 0.f;
            if (w == 3) { A = __expf(A_log[n]); bd = b_delta[n]; }
#pragma unroll
            for (int r = 0; r < 4; r++) {
                int m = m0 + wm + i * 16 + quad * 4 + r;
                float z = acc[i][j][r];
                float o;
                if (w == 0) {
                    o = z;                                    // raw
                } else if (w == 1) {
                    o = 1.f / (1.f + __expf(-z));             // sigmoid gate
                } else if (w == 2) {
                    o = 1.f + tanh_fast(z);                   // 1 + mod
                } else {
                    float v = z + bd;                         // softplus, stable
                    float sp = fmaxf(v, 0.f) + __logf(1.f + __expf(-fabsf(v)));
                    o = 1.f - __expf(-A * sp);                // 1 - decay
                }
                Op[(size_t)m * DN + n] = f2bf(o);
            }
        }
    }
}

// ---------------- output GEMM: out[m][dm] = sum_k Z[m][k]*W_out[dm][k], K=4096 ----------------
__global__ __launch_bounds__(256, 4) void gemm_out_kernel(
    const u16* __restrict__ Zb, const u16* __restrict__ Wob, float* __restrict__ Out)
{
    const int n0 = blockIdx.x * BN;
    const int m0 = blockIdx.y * BM;

    alignas(16) __shared__ u16 As[BM * BK];
    alignas(16) __shared__ u16 Bs[BN * BK];

    const int tid = threadIdx.x;
    const int lane = tid & 63;
    const int wave = tid >> 6;
    const int wm = (wave >> 1) * 64;
    const int wn = (wave & 1) * 64;
    const int l16 = lane & 15;
    const int quad = lane >> 4;
    const int sr8 = lane >> 3;
    const int cl = lane & 7;

    const f32x4 z4 = {0.f, 0.f, 0.f, 0.f};
    f32x4 acc[4][4];
#pragma unroll
    for (int i = 0; i < 4; i++)
#pragma unroll
        for (int j = 0; j < 4; j++) acc[i][j] = z4;

    for (int kt = 0; kt < DN; kt += BK) {
        __syncthreads();
#pragma unroll
        for (int it = 0; it < 4; ++it) {
            const int r = wave * 32 + it * 8 + sr8;
            const int cg = cl ^ (r & 7);
            async16(Zb + (size_t)(m0 + r) * DN + kt + cg * 8,
                    As + (wave * 32 + it * 8) * BK);
            async16(Wob + (size_t)(n0 + r) * DN + kt + cg * 8,
                    Bs + (wave * 32 + it * 8) * BK);
        }
        __syncthreads();
#pragma unroll
        for (int ks = 0; ks < BK; ks += 32) {
            bf16x8 af[4], bfr[4];
#pragma unroll
            for (int i = 0; i < 4; i++) {
                const int r = wm + i * 16 + l16;
                const int ch = ((ks >> 3) + quad) ^ (r & 7);
                af[i] = *(const bf16x8*)(As + r * BK + ch * 8);
            }
#pragma unroll
            for (int j = 0; j < 4; j++) {
                const int r = wn + j * 16 + l16;
                const int ch = ((ks >> 3) + quad) ^ (r & 7);
                bfr[j] = *(const bf16x8*)(Bs + r * BK + ch * 8);
            }
#pragma unroll
            for (int i = 0; i < 4; i++)
#pragma unroll
                for (int j = 0; j < 4; j++)
                    acc[i][j] = __builtin_amdgcn_mfma_f32_16x16x32_bf16(af[i], bfr[j], acc[i][j], 0, 0, 0);
        }
    }

#pragma unroll
    for (int i = 0; i < 4; i++)
#pragma unroll
        for (int j = 0; j < 4; j++) {
            int n = n0 + wn + j * 16 + l16;
#pragma unroll
            for (int r = 0; r < 4; r++) {
                int m = m0 + wm + i * 16 + quad * 4 + r;
                Out[(size_t)m * DM + n] = acc[i][j][r];
            }
        }
}

// ---------------- scan pass 1: per-sub-chunk decay product + partial state ----------------
__global__ void scan_pass1(const u16* __restrict__ omd_a, const u16* __restrict__ sig_a,
                           const u16* __restrict__ raw_a,
                           float* __restrict__ Dc, float* __restrict__ Sc)
{
    int tid = threadIdx.x;
    int bx = blockIdx.x;              // BB*NSC*16 = 512 blocks
    int nb = bx & 15;
    int sc = (bx >> 4) & (NSC - 1);
    int b = bx >> 8;
    int n = nb * 256 + tid;
    size_t base = ((size_t)(b * TC + sc * SCH)) * DN + n;
    float D = 1.f, s = 0.f;
#pragma unroll 8
    for (int t = 0; t < SCH; t++) {
        size_t idx = base + (size_t)t * DN;
        float omd = bf2f(omd_a[idx]);
        float sg = bf2f(sig_a[idx]);
        float rw = bf2f(raw_a[idx]);
        float d = 1.f - omd;
        float u = omd * sg * tanh_fast(rw);
        D *= d;
        s = d * s + u;
    }
    int ci = (b * NSC + sc) * DN + n;
    Dc[ci] = D;
    Sc[ci] = s;
}

// ---------------- scan pass 2+3 fused: inline chunk-combine, re-scan, emit Z ----------------
__global__ void scan_pass23(const u16* __restrict__ omd_a, const u16* __restrict__ sig_a,
                            const u16* __restrict__ raw_a, const u16* __restrict__ modp_a,
                            const float* __restrict__ Dc, const float* __restrict__ Sc,
                            const float* __restrict__ state_in, float* __restrict__ state_out,
                            const float* __restrict__ sw_logit,
                            u16* __restrict__ Z, float* __restrict__ fs_out, int ci_t)
{
    int tid = threadIdx.x;
    int bx = blockIdx.x;              // 512 blocks
    int nb = bx & 15;
    int sc = (bx >> 4) & (NSC - 1);
    int b = bx >> 8;
    int n = nb * 256 + tid;

    // combine sub-chunk summaries 0..sc-1 on the fly
    float s = state_in[b * DN + n];
    for (int c = 0; c < sc; c++) {
        int ci = (b * NSC + c) * DN + n;
        s = Dc[ci] * s + Sc[ci];
    }

    size_t lbase = ((size_t)(b * TC + sc * SCH)) * DN + n;
    size_t gbase = ((size_t)(b * TT + ci_t * TC + sc * SCH)) * DN + n;
    float sw = 1.f / (1.f + __expf(-sw_logit[n]));
    float osw = 1.f - sw;
#pragma unroll 8
    for (int t = 0; t < SCH; t++) {
        size_t li = lbase + (size_t)t * DN;
        float omd = bf2f(omd_a[li]);
        float sg = bf2f(sig_a[li]);
        float rw = bf2f(raw_a[li]);
        float mp = bf2f(modp_a[li]);
        float d = 1.f - omd;
        float u = omd * sg * tanh_fast(rw);
        s = d * s + u;
        float g = 0.5f * rw * (1.f + erf_fast(rw * 0.70710678f));  // exact gelu
        Z[gbase + (size_t)t * DN] = f2bf(mp * (osw * g + sw * s));
    }
    if (sc == NSC - 1) {
        state_out[b * DN + n] = s;    // carry to next chunk
        fs_out[b * DN + n] = s;       // last chunk's write is final_state
    }
}

// ---------------- host launcher ----------------
extern "C" void kernel_launch(void* const* d_in, const int* in_sizes, int n_in,
                              void* d_out, int out_size, void* d_ws, size_t ws_size,
                              hipStream_t stream)
{
    const float* x = (const float*)d_in[0];
    const float* state = (const float*)d_in[1];
    const float* W_main = (const float*)d_in[2];
    const float* W_gate = (const float*)d_in[3];
    const float* W_mod = (const float*)d_in[4];
    const float* W_out = (const float*)d_in[5];
    const float* W_delta = (const float*)d_in[6];
    const float* b_delta = (const float*)d_in[7];
    const float* A_log = (const float*)d_in[8];
    const float* sw_logit = (const float*)d_in[9];

    float* out = (float*)d_out;                       // [B,T,Dm] fp32
    float* fs_out = out + (size_t)MR * DM;            // final_state [B,Dn]

    const size_t NM = (size_t)MR * DN;
    u16* Zb = (u16*)d_ws;                             // 67.11 MB
    u16* raw_c = Zb + NM;                             // 4 x 8.39 MB
    u16* sig_c = raw_c + CN;
    u16* modp_c = sig_c + CN;
    u16* omd_c = modp_c + CN;
    u16* W4b = omd_c + CN;                            // 33.55 MB
    u16* xb = W4b + (size_t)4 * DN * DM;              // 16.78 MB
    // union region D (8.39 MB): Dc/Sc/state ping-pong during the loop,
    // then woutb after the loop (Dc/Sc dead by then; same-stream ordering).
    char* regD = (char*)(xb + (size_t)MR * DM);
    float* Dc = (float*)regD;                         // 524,288 B
    float* Sc = Dc + (size_t)BB * NSC * DN;           // 524,288 B
    float* st0 = Sc + (size_t)BB * NSC * DN;          // 32,768 B
    float* st1 = st0 + (size_t)BB * DN;               // 32,768 B
    u16* woutb = (u16*)regD;                          // 8,388,608 B (aliases Dc/Sc/st)
    // total = 159,383,552 B  (< 160,202,752 proven available in round 3)

    hipMemcpyAsync(st0, state, (size_t)BB * DN * sizeof(float),
                   hipMemcpyDeviceToDevice, stream);

    // one fused conversion launch: x + 4 projection weights
    {
        const int total4 = (MR * DM) / 4 + 4 * ((DN * DM) / 4);   // 6,291,456
        cvt5_kernel<<<total4 / 256, 256, 0, stream>>>(
            (const float4*)x, (const float4*)W_main, (const float4*)W_gate,
            (const float4*)W_mod, (const float4*)W_delta,
            (ushort4*)xb, (ushort4*)W4b);
    }

    dim3 gridA(DN / BN, CR / BM, 4);                  // 32 x 8 x 4 = 1024 blocks
    for (int ci = 0; ci < NTC; ci++) {
        float* sin  = (ci & 1) ? st1 : st0;
        float* sout = (ci & 1) ? st0 : st1;
        gemm4_kernel<<<gridA, 256, 0, stream>>>(xb, W4b, raw_c, sig_c, modp_c, omd_c,
                                                A_log, b_delta, ci);
        scan_pass1<<<BB * NSC * 16, 256, 0, stream>>>(omd_c, sig_c, raw_c, Dc, Sc);
        scan_pass23<<<BB * NSC * 16, 256, 0, stream>>>(omd_c, sig_c, raw_c, modp_c,
                                                       Dc, Sc, sin, sout, sw_logit,
                                                       Zb, fs_out, ci);
    }

    // W_out conversion (region D is dead now), then output projection
    cvt_kernel<<<(DN * DM / 4) / 256, 256, 0, stream>>>((const float4*)W_out,
                                                        (ushort4*)woutb, DN * DM / 4);
    dim3 gridB(DM / BN, MR / BM, 1);                  // 8 x 64 = 512 blocks
    gemm_out_kernel<<<gridB, 256, 0, stream>>>(Zb, woutb, out);
}

// Round 5
// 975.373 us; speedup vs baseline: 1.8823x; 1.0110x over previous
//
#include <hip/hip_runtime.h>
#include <hip/hip_bf16.h>
#include <stdint.h>

#define DM 1024            // d_model
#define DN 4096            // d_neuron
#define BB 2               // batch
#define TT 4096            // seq
#define MR (BB*TT)         // 8192 total GEMM rows
#define TC 512             // time chunk
#define NTC (TT/TC)        // 8 time chunks
#define CR (BB*TC)         // 1024 rows per chunk
#define CN ((size_t)CR*DN) // per-chunk activation elems (4,194,304)
#define SCH 32             // scan sub-chunk
#define NSC (TC/SCH)       // 16 sub-chunks per time chunk

typedef unsigned short u16;
typedef __attribute__((ext_vector_type(8))) short bf16x8;
typedef __attribute__((ext_vector_type(4))) float f32x4;

__device__ __forceinline__ float bf2f(u16 u) {
    unsigned int x = ((unsigned int)u) << 16; float f; __builtin_memcpy(&f, &x, 4); return f;
}
__device__ __forceinline__ u16 f2bf(float f) {
    __hip_bfloat16 h = __float2bfloat16(f); u16 u; __builtin_memcpy(&u, &h, 2); return u;
}
// fast tanh: 1 - 2/(exp(2x)+1); exact at +-inf, abs err ~1e-7
__device__ __forceinline__ float tanh_fast(float x) {
    float e = __expf(2.f * x);
    return 1.f - 2.f / (e + 1.f);
}
// A&S 7.1.26 erf poly, max abs err 1.5e-7
__device__ __forceinline__ float erf_fast(float x) {
    float ax = fabsf(x);
    float t = 1.f / (1.f + 0.3275911f * ax);
    float y = t * (0.254829592f + t * (-0.284496736f + t * (1.421413741f +
              t * (-1.453152027f + t * 1.061405429f))));
    float r = 1.f - y * __expf(-ax * ax);
    return copysignf(r, x);
}
// async global->LDS, 16 B per lane (dest = wave-uniform base + lane*16)
__device__ __forceinline__ void async16(const void* g, void* l) {
    __builtin_amdgcn_global_load_lds(
        (const __attribute__((address_space(1))) void*)(uintptr_t)g,
        (__attribute__((address_space(3))) void*)(uint32_t)(uintptr_t)l,
        16, 0, 0);
}

// ---------------- fused fp32 -> bf16 conversion: x + 4 projection weights ----------------
__global__ void cvt5_kernel(const float4* __restrict__ x,
                            const float4* __restrict__ w0, const float4* __restrict__ w1,
                            const float4* __restrict__ w2, const float4* __restrict__ w3,
                            ushort4* __restrict__ xb, ushort4* __restrict__ w4b)
{
    const int XQ = (MR * DM) / 4;        // 2,097,152
    const int WQ = (DN * DM) / 4;        // 1,048,576 = 2^20
    int i = blockIdx.x * 256 + threadIdx.x;
    const float4* s; ushort4* d;
    if (i < XQ) { s = x + i; d = xb + i; }
    else {
        int j = i - XQ;
        int seg = j >> 20;
        int off = j & (WQ - 1);
        const float4* ws = (seg == 0) ? w0 : (seg == 1) ? w1 : (seg == 2) ? w2 : w3;
        s = ws + off; d = w4b + j;
    }
    float4 v = *s;
    ushort4 o; o.x = f2bf(v.x); o.y = f2bf(v.y); o.z = f2bf(v.z); o.w = f2bf(v.w);
    *d = o;
}

__global__ void cvt_kernel(const float4* __restrict__ src, ushort4* __restrict__ dst, int n4) {
    int i = blockIdx.x * 256 + threadIdx.x;
    if (i < n4) {
        float4 v = src[i];
        ushort4 o; o.x = f2bf(v.x); o.y = f2bf(v.y); o.z = f2bf(v.z); o.w = f2bf(v.w);
        dst[i] = o;
    }
}

#define BM 128
#define BN 128
#define BK 64

// ---------------- 4 input projections for one time chunk, fused activations ----------------
// XCD-aware swizzle: 1024 blocks all co-resident (4/CU). blockIdx%8 = XCD (heuristic).
// XCD x owns (n,w) pairs [x*16, x*16+16); the 8 m-blocks of a pair are co-resident on
// XCD x -> W-tile working set per XCD = 16 x 256KB = 4MB = L2 size; W read ~once total.
__global__ __launch_bounds__(256, 4) void gemm4_kernel(
    const u16* __restrict__ Xb,             // bf16 [8192][1024]
    const u16* __restrict__ W4b,            // bf16 [4][4096][1024]
    u16* __restrict__ raw_o, u16* __restrict__ sig_o,
    u16* __restrict__ modp_o, u16* __restrict__ omd_o,
    const float* __restrict__ A_log, const float* __restrict__ b_delta, int ci)
{
    const int bid = blockIdx.x;              // 0..1023
    const int xcd = bid & 7;
    const int g = bid >> 3;                  // 0..127
    const int m_idx = g & 7;
    const int pair = xcd * 16 + (g >> 3);    // 0..127 = 32 n-tiles x 4 w
    const int n_idx = pair & 31;
    const int w = pair >> 5;

    const u16* Wp = W4b + (size_t)w * DN * DM;
    u16* Op = (w == 0) ? raw_o : (w == 1) ? sig_o : (w == 2) ? modp_o : omd_o;
    const int n0 = n_idx * BN;
    const int m0 = m_idx * BM;

    alignas(16) __shared__ u16 As[BM * BK];
    alignas(16) __shared__ u16 Bs[BN * BK];

    const int tid = threadIdx.x;
    const int lane = tid & 63;
    const int wave = tid >> 6;
    const int wm = (wave >> 1) * 64;
    const int wn = (wave & 1) * 64;
    const int l16 = lane & 15;
    const int quad = lane >> 4;
    const int sr8 = lane >> 3;
    const int cl = lane & 7;

    const f32x4 z4 = {0.f, 0.f, 0.f, 0.f};
    f32x4 acc[4][4];
#pragma unroll
    for (int i = 0; i < 4; i++)
#pragma unroll
        for (int j = 0; j < 4; j++) acc[i][j] = z4;

    for (int kt = 0; kt < DM; kt += BK) {
        __syncthreads();
#pragma unroll
        for (int it = 0; it < 4; ++it) {
            const int r = wave * 32 + it * 8 + sr8;
            const int cg = cl ^ (r & 7);                  // XOR-8 swizzle
            async16(Wp + (size_t)(n0 + r) * DM + kt + cg * 8,
                    Bs + (wave * 32 + it * 8) * BK);
            const int lr = m0 + r;
            const int xrow = ((lr >> 9) << 12) + ci * TC + (lr & (TC - 1));
            async16(Xb + (size_t)xrow * DM + kt + cg * 8,
                    As + (wave * 32 + it * 8) * BK);
        }
        __syncthreads();
#pragma unroll
        for (int ks = 0; ks < BK; ks += 32) {
            bf16x8 af[4], bfr[4];
#pragma unroll
            for (int i = 0; i < 4; i++) {
                const int r = wm + i * 16 + l16;
                const int ch = ((ks >> 3) + quad) ^ (r & 7);
                af[i] = *(const bf16x8*)(As + r * BK + ch * 8);
            }
#pragma unroll
            for (int j = 0; j < 4; j++) {
                const int r = wn + j * 16 + l16;
                const int ch = ((ks >> 3) + quad) ^ (r & 7);
                bfr[j] = *(const bf16x8*)(Bs + r * BK + ch * 8);
            }
#pragma unroll
            for (int i = 0; i < 4; i++)
#pragma unroll
                for (int j = 0; j < 4; j++)
                    acc[i][j] = __builtin_amdgcn_mfma_f32_16x16x32_bf16(af[i], bfr[j], acc[i][j], 0, 0, 0);
        }
    }

    // hoisted per-column params for w=3 (n depends only on j)
    float Aj[4], bdj[4];
    if (w == 3) {
#pragma unroll
        for (int j = 0; j < 4; j++) {
            int n = n0 + wn + j * 16 + l16;
            Aj[j] = __expf(A_log[n]);
            bdj[j] = b_delta[n];
        }
    }

    // epilogue: C/D layout col=lane&15, row=quad*4+reg (m89-verified)
#pragma unroll
    for (int i = 0; i < 4; i++) {
#pragma unroll
        for (int j = 0; j < 4; j++) {
            int n = n0 + wn + j * 16 + l16;
#pragma unroll
            for (int r = 0; r < 4; r++) {
                int m = m0 + wm + i * 16 + quad * 4 + r;
                float z = acc[i][j][r];
                float o;
                if (w == 0) {
                    o = z;                                    // raw
                } else if (w == 1) {
                    o = 1.f / (1.f + __expf(-z));             // sigmoid gate
                } else if (w == 2) {
                    o = 1.f + tanh_fast(z);                   // 1 + mod
                } else {
                    float v = z + bdj[j];                     // softplus, stable
                    float sp = fmaxf(v, 0.f) + __logf(1.f + __expf(-fabsf(v)));
                    o = 1.f - __expf(-Aj[j] * sp);            // 1 - decay
                }
                Op[(size_t)m * DN + n] = f2bf(o);
            }
        }
    }
}

// ---------------- output GEMM: out[m][dm] = sum_k Z[m][k]*W_out[dm][k], K=4096 ----------------
// XCD swizzle: XCD x owns m-tiles [x*8, x*8+8); the 8 n-blocks of one m-tile co-resident
// on one XCD -> Z tile fetched ~once per XCD; Wout n-slices L2-cached per kt window.
__global__ __launch_bounds__(256, 4) void gemm_out_kernel(
    const u16* __restrict__ Zb, const u16* __restrict__ Wob, float* __restrict__ Out)
{
    const int bid = blockIdx.x;              // 0..511
    const int xcd = bid & 7;
    const int g = bid >> 3;                  // 0..63
    const int n_idx = g & 7;
    const int m_idx = xcd * 8 + (g >> 3);    // 0..63
    const int n0 = n_idx * BN;
    const int m0 = m_idx * BM;

    alignas(16) __shared__ u16 As[BM * BK];
    alignas(16) __shared__ u16 Bs[BN * BK];

    const int tid = threadIdx.x;
    const int lane = tid & 63;
    const int wave = tid >> 6;
    const int wm = (wave >> 1) * 64;
    const int wn = (wave & 1) * 64;
    const int l16 = lane & 15;
    const int quad = lane >> 4;
    const int sr8 = lane >> 3;
    const int cl = lane & 7;

    const f32x4 z4 = {0.f, 0.f, 0.f, 0.f};
    f32x4 acc[4][4];
#pragma unroll
    for (int i = 0; i < 4; i++)
#pragma unroll
        for (int j = 0; j < 4; j++) acc[i][j] = z4;

    for (int kt = 0; kt < DN; kt += BK) {
        __syncthreads();
#pragma unroll
        for (int it = 0; it < 4; ++it) {
            const int r = wave * 32 + it * 8 + sr8;
            const int cg = cl ^ (r & 7);
            async16(Zb + (size_t)(m0 + r) * DN + kt + cg * 8,
                    As + (wave * 32 + it * 8) * BK);
            async16(Wob + (size_t)(n0 + r) * DN + kt + cg * 8,
                    Bs + (wave * 32 + it * 8) * BK);
        }
        __syncthreads();
#pragma unroll
        for (int ks = 0; ks < BK; ks += 32) {
            bf16x8 af[4], bfr[4];
#pragma unroll
            for (int i = 0; i < 4; i++) {
                const int r = wm + i * 16 + l16;
                const int ch = ((ks >> 3) + quad) ^ (r & 7);
                af[i] = *(const bf16x8*)(As + r * BK + ch * 8);
            }
#pragma unroll
            for (int j = 0; j < 4; j++) {
                const int r = wn + j * 16 + l16;
                const int ch = ((ks >> 3) + quad) ^ (r & 7);
                bfr[j] = *(const bf16x8*)(Bs + r * BK + ch * 8);
            }
#pragma unroll
            for (int i = 0; i < 4; i++)
#pragma unroll
                for (int j = 0; j < 4; j++)
                    acc[i][j] = __builtin_amdgcn_mfma_f32_16x16x32_bf16(af[i], bfr[j], acc[i][j], 0, 0, 0);
        }
    }

#pragma unroll
    for (int i = 0; i < 4; i++)
#pragma unroll
        for (int j = 0; j < 4; j++) {
            int n = n0 + wn + j * 16 + l16;
#pragma unroll
            for (int r = 0; r < 4; r++) {
                int m = m0 + wm + i * 16 + quad * 4 + r;
                Out[(size_t)m * DM + n] = acc[i][j][r];
            }
        }
}

// ---------------- scan pass 1: per-sub-chunk decay product + partial state ----------------
__global__ void scan_pass1(const u16* __restrict__ omd_a, const u16* __restrict__ sig_a,
                           const u16* __restrict__ raw_a,
                           float* __restrict__ Dc, float* __restrict__ Sc)
{
    int tid = threadIdx.x;
    int bx = blockIdx.x;              // BB*NSC*16 = 512 blocks
    int nb = bx & 15;
    int sc = (bx >> 4) & (NSC - 1);
    int b = bx >> 8;
    int n = nb * 256 + tid;
    size_t base = ((size_t)(b * TC + sc * SCH)) * DN + n;
    float D = 1.f, s = 0.f;
#pragma unroll 8
    for (int t = 0; t < SCH; t++) {
        size_t idx = base + (size_t)t * DN;
        float omd = bf2f(omd_a[idx]);
        float sg = bf2f(sig_a[idx]);
        float rw = bf2f(raw_a[idx]);
        float d = 1.f - omd;
        float u = omd * sg * tanh_fast(rw);
        D *= d;
        s = d * s + u;
    }
    int ci = (b * NSC + sc) * DN + n;
    Dc[ci] = D;
    Sc[ci] = s;
}

// ---------------- scan pass 2+3 fused: inline chunk-combine, re-scan, emit Z ----------------
__global__ void scan_pass23(const u16* __restrict__ omd_a, const u16* __restrict__ sig_a,
                            const u16* __restrict__ raw_a, const u16* __restrict__ modp_a,
                            const float* __restrict__ Dc, const float* __restrict__ Sc,
                            const float* __restrict__ state_in, float* __restrict__ state_out,
                            const float* __restrict__ sw_logit,
                            u16* __restrict__ Z, float* __restrict__ fs_out, int ci_t)
{
    int tid = threadIdx.x;
    int bx = blockIdx.x;              // 512 blocks
    int nb = bx & 15;
    int sc = (bx >> 4) & (NSC - 1);
    int b = bx >> 8;
    int n = nb * 256 + tid;

    // combine sub-chunk summaries 0..sc-1 on the fly
    float s = state_in[b * DN + n];
    for (int c = 0; c < sc; c++) {
        int ci = (b * NSC + c) * DN + n;
        s = Dc[ci] * s + Sc[ci];
    }

    size_t lbase = ((size_t)(b * TC + sc * SCH)) * DN + n;
    size_t gbase = ((size_t)(b * TT + ci_t * TC + sc * SCH)) * DN + n;
    float sw = 1.f / (1.f + __expf(-sw_logit[n]));
    float osw = 1.f - sw;
#pragma unroll 8
    for (int t = 0; t < SCH; t++) {
        size_t li = lbase + (size_t)t * DN;
        float omd = bf2f(omd_a[li]);
        float sg = bf2f(sig_a[li]);
        float rw = bf2f(raw_a[li]);
        float mp = bf2f(modp_a[li]);
        float d = 1.f - omd;
        float u = omd * sg * tanh_fast(rw);
        s = d * s + u;
        float g2 = 0.5f * rw * (1.f + erf_fast(rw * 0.70710678f));  // exact gelu
        Z[gbase + (size_t)t * DN] = f2bf(mp * (osw * g2 + sw * s));
    }
    if (sc == NSC - 1) {
        state_out[b * DN + n] = s;    // carry to next chunk
        fs_out[b * DN + n] = s;       // last chunk's write is final_state
    }
}

// ---------------- host launcher ----------------
extern "C" void kernel_launch(void* const* d_in, const int* in_sizes, int n_in,
                              void* d_out, int out_size, void* d_ws, size_t ws_size,
                              hipStream_t stream)
{
    const float* x = (const float*)d_in[0];
    const float* state = (const float*)d_in[1];
    const float* W_main = (const float*)d_in[2];
    const float* W_gate = (const float*)d_in[3];
    const float* W_mod = (const float*)d_in[4];
    const float* W_out = (const float*)d_in[5];
    const float* W_delta = (const float*)d_in[6];
    const float* b_delta = (const float*)d_in[7];
    const float* A_log = (const float*)d_in[8];
    const float* sw_logit = (const float*)d_in[9];

    float* out = (float*)d_out;                       // [B,T,Dm] fp32
    float* fs_out = out + (size_t)MR * DM;            // final_state [B,Dn]

    const size_t NM = (size_t)MR * DN;
    u16* Zb = (u16*)d_ws;                             // 67.11 MB
    u16* raw_c = Zb + NM;                             // 4 x 8.39 MB
    u16* sig_c = raw_c + CN;
    u16* modp_c = sig_c + CN;
    u16* omd_c = modp_c + CN;
    u16* W4b = omd_c + CN;                            // 33.55 MB
    u16* xb = W4b + (size_t)4 * DN * DM;              // 16.78 MB
    // union region D (8.39 MB): Dc/Sc/state ping-pong during the loop,
    // then woutb after the loop (Dc/Sc dead by then; same-stream ordering).
    char* regD = (char*)(xb + (size_t)MR * DM);
    float* Dc = (float*)regD;                         // 524,288 B
    float* Sc = Dc + (size_t)BB * NSC * DN;           // 524,288 B
    float* st0 = Sc + (size_t)BB * NSC * DN;          // 32,768 B
    float* st1 = st0 + (size_t)BB * DN;               // 32,768 B
    u16* woutb = (u16*)regD;                          // 8,388,608 B (aliases Dc/Sc/st)
    // total = 159,383,552 B  (< 160,202,752 proven available in round 3)

    hipMemcpyAsync(st0, state, (size_t)BB * DN * sizeof(float),
                   hipMemcpyDeviceToDevice, stream);

    // one fused conversion launch: x + 4 projection weights
    {
        const int total4 = (MR * DM) / 4 + 4 * ((DN * DM) / 4);   // 6,291,456
        cvt5_kernel<<<total4 / 256, 256, 0, stream>>>(
            (const float4*)x, (const float4*)W_main, (const float4*)W_gate,
            (const float4*)W_mod, (const float4*)W_delta,
            (ushort4*)xb, (ushort4*)W4b);
    }

    for (int ci = 0; ci < NTC; ci++) {
        float* sin  = (ci & 1) ? st1 : st0;
        float* sout = (ci & 1) ? st0 : st1;
        gemm4_kernel<<<1024, 256, 0, stream>>>(xb, W4b, raw_c, sig_c, modp_c, omd_c,
                                               A_log, b_delta, ci);
        scan_pass1<<<BB * NSC * 16, 256, 0, stream>>>(omd_c, sig_c, raw_c, Dc, Sc);
        scan_pass23<<<BB * NSC * 16, 256, 0, stream>>>(omd_c, sig_c, raw_c, modp_c,
                                                       Dc, Sc, sin, sout, sw_logit,
                                                       Zb, fs_out, ci);
    }

    // W_out conversion (region D is dead now), then output projection
    cvt_kernel<<<(DN * DM / 4) / 256, 256, 0, stream>>>((const float4*)W_out,
                                                        (ushort4*)woutb, DN * DM / 4);
    gemm_out_kernel<<<512, 256, 0, stream>>>(Zb, woutb, out);
}

// Round 6
// 836.412 us; speedup vs baseline: 2.1950x; 1.1661x over previous
//
#include <hip/hip_runtime.h>
#include <hip/hip_bf16.h>
#include <stdint.h>

#define DM 1024            // d_model
#define DN 4096            // d_neuron
#define BB 2               // batch
#define TT 4096            // seq
#define MR (BB*TT)         // 8192 total GEMM rows
#define TC 512             // time chunk
#define NTC (TT/TC)        // 8 time chunks
#define CR (BB*TC)         // 1024 rows per chunk
#define CN ((size_t)CR*DN) // per-chunk activation elems (4,194,304)
#define SCH 16             // scan sub-chunk (32 tg x 16 = TC)

typedef unsigned short u16;
typedef __attribute__((ext_vector_type(8))) short bf16x8;
typedef __attribute__((ext_vector_type(4))) float f32x4;

__device__ __forceinline__ float bf2f(u16 u) {
    unsigned int x = ((unsigned int)u) << 16; float f; __builtin_memcpy(&f, &x, 4); return f;
}
__device__ __forceinline__ u16 f2bf(float f) {
    __hip_bfloat16 h = __float2bfloat16(f); u16 u; __builtin_memcpy(&u, &h, 2); return u;
}
// fast tanh: 1 - 2/(exp(2x)+1); exact at +-inf, abs err ~1e-7
__device__ __forceinline__ float tanh_fast(float x) {
    float e = __expf(2.f * x);
    return 1.f - 2.f / (e + 1.f);
}
// A&S 7.1.26 erf poly, max abs err 1.5e-7
__device__ __forceinline__ float erf_fast(float x) {
    float ax = fabsf(x);
    float t = 1.f / (1.f + 0.3275911f * ax);
    float y = t * (0.254829592f + t * (-0.284496736f + t * (1.421413741f +
              t * (-1.453152027f + t * 1.061405429f))));
    float r = 1.f - y * __expf(-ax * ax);
    return copysignf(r, x);
}
// async global->LDS, 16 B per lane (dest = wave-uniform base + lane*16)
__device__ __forceinline__ void async16(const void* g, void* l) {
    __builtin_amdgcn_global_load_lds(
        (const __attribute__((address_space(1))) void*)(uintptr_t)g,
        (__attribute__((address_space(3))) void*)(uint32_t)(uintptr_t)l,
        16, 0, 0);
}

// ---------------- fused fp32 -> bf16 conversion: x + 4 proj weights + W_out ----------------
__global__ void cvt6_kernel(const float4* __restrict__ x,
                            const float4* __restrict__ w0, const float4* __restrict__ w1,
                            const float4* __restrict__ w2, const float4* __restrict__ w3,
                            const float4* __restrict__ wo,
                            ushort4* __restrict__ xb, ushort4* __restrict__ w4b,
                            ushort4* __restrict__ woutb)
{
    const int XQ = (MR * DM) / 4;        // 2,097,152
    const int WQ = (DN * DM) / 4;        // 1,048,576 = 2^20
    int i = blockIdx.x * 256 + threadIdx.x;
    const float4* s; ushort4* d;
    if (i < XQ) { s = x + i; d = xb + i; }
    else {
        int j = i - XQ;
        int seg = j >> 20;
        int off = j & (WQ - 1);
        if (seg < 4) {
            const float4* ws = (seg == 0) ? w0 : (seg == 1) ? w1 : (seg == 2) ? w2 : w3;
            s = ws + off; d = w4b + j;
        } else {
            s = wo + off; d = woutb + off;
        }
    }
    float4 v = *s;
    ushort4 o; o.x = f2bf(v.x); o.y = f2bf(v.y); o.z = f2bf(v.z); o.w = f2bf(v.w);
    *d = o;
}

#define BM 128
#define BN 128
#define BK 64

// ---------------- 4 input projections for one time chunk, fused activations ----------------
// XCD-aware swizzle: XCD x owns (n,w) pairs [x*16, x*16+16); 8 m-blocks per pair co-resident
// -> per-XCD W working set 4MB = L2 size (verified: round-5 FETCH cratered on gemm_out).
__global__ __launch_bounds__(256, 4) void gemm4_kernel(
    const u16* __restrict__ Xb,             // bf16 [8192][1024]
    const u16* __restrict__ W4b,            // bf16 [4][4096][1024]
    u16* __restrict__ raw_o, u16* __restrict__ sig_o,
    u16* __restrict__ modp_o, u16* __restrict__ omd_o,
    const float* __restrict__ A_log, const float* __restrict__ b_delta, int ci)
{
    const int bid = blockIdx.x;              // 0..1023
    const int xcd = bid & 7;
    const int g = bid >> 3;                  // 0..127
    const int m_idx = g & 7;
    const int pair = xcd * 16 + (g >> 3);    // 0..127 = 32 n-tiles x 4 w
    const int n_idx = pair & 31;
    const int w = pair >> 5;

    const u16* Wp = W4b + (size_t)w * DN * DM;
    u16* Op = (w == 0) ? raw_o : (w == 1) ? sig_o : (w == 2) ? modp_o : omd_o;
    const int n0 = n_idx * BN;
    const int m0 = m_idx * BM;

    alignas(16) __shared__ u16 As[BM * BK];
    alignas(16) __shared__ u16 Bs[BN * BK];

    const int tid = threadIdx.x;
    const int lane = tid & 63;
    const int wave = tid >> 6;
    const int wm = (wave >> 1) * 64;
    const int wn = (wave & 1) * 64;
    const int l16 = lane & 15;
    const int quad = lane >> 4;
    const int sr8 = lane >> 3;
    const int cl = lane & 7;

    const f32x4 z4 = {0.f, 0.f, 0.f, 0.f};
    f32x4 acc[4][4];
#pragma unroll
    for (int i = 0; i < 4; i++)
#pragma unroll
        for (int j = 0; j < 4; j++) acc[i][j] = z4;

    for (int kt = 0; kt < DM; kt += BK) {
        __syncthreads();
#pragma unroll
        for (int it = 0; it < 4; ++it) {
            const int r = wave * 32 + it * 8 + sr8;
            const int cg = cl ^ (r & 7);                  // XOR-8 swizzle
            async16(Wp + (size_t)(n0 + r) * DM + kt + cg * 8,
                    Bs + (wave * 32 + it * 8) * BK);
            const int lr = m0 + r;
            const int xrow = ((lr >> 9) << 12) + ci * TC + (lr & (TC - 1));
            async16(Xb + (size_t)xrow * DM + kt + cg * 8,
                    As + (wave * 32 + it * 8) * BK);
        }
        __syncthreads();
#pragma unroll
        for (int ks = 0; ks < BK; ks += 32) {
            bf16x8 af[4], bfr[4];
#pragma unroll
            for (int i = 0; i < 4; i++) {
                const int r = wm + i * 16 + l16;
                const int ch = ((ks >> 3) + quad) ^ (r & 7);
                af[i] = *(const bf16x8*)(As + r * BK + ch * 8);
            }
#pragma unroll
            for (int j = 0; j < 4; j++) {
                const int r = wn + j * 16 + l16;
                const int ch = ((ks >> 3) + quad) ^ (r & 7);
                bfr[j] = *(const bf16x8*)(Bs + r * BK + ch * 8);
            }
#pragma unroll
            for (int i = 0; i < 4; i++)
#pragma unroll
                for (int j = 0; j < 4; j++)
                    acc[i][j] = __builtin_amdgcn_mfma_f32_16x16x32_bf16(af[i], bfr[j], acc[i][j], 0, 0, 0);
        }
    }

    // hoisted per-column params for w=3 (n depends only on j)
    float Aj[4], bdj[4];
    if (w == 3) {
#pragma unroll
        for (int j = 0; j < 4; j++) {
            int n = n0 + wn + j * 16 + l16;
            Aj[j] = __expf(A_log[n]);
            bdj[j] = b_delta[n];
        }
    }

    // epilogue: C/D layout col=lane&15, row=quad*4+reg (m89-verified)
#pragma unroll
    for (int i = 0; i < 4; i++) {
#pragma unroll
        for (int j = 0; j < 4; j++) {
            int n = n0 + wn + j * 16 + l16;
#pragma unroll
            for (int r = 0; r < 4; r++) {
                int m = m0 + wm + i * 16 + quad * 4 + r;
                float z = acc[i][j][r];
                float o;
                if (w == 0) {
                    o = z;                                    // raw
                } else if (w == 1) {
                    o = 1.f / (1.f + __expf(-z));             // sigmoid gate
                } else if (w == 2) {
                    o = 1.f + tanh_fast(z);                   // 1 + mod
                } else {
                    float v = z + bdj[j];                     // softplus, stable
                    float sp = fmaxf(v, 0.f) + __logf(1.f + __expf(-fabsf(v)));
                    o = 1.f - __expf(-Aj[j] * sp);            // 1 - decay
                }
                Op[(size_t)m * DN + n] = f2bf(o);
            }
        }
    }
}

// ---------------- output GEMM: out[m][dm] = sum_k Z[m][k]*W_out[dm][k], K=4096 ----------------
__global__ __launch_bounds__(256, 4) void gemm_out_kernel(
    const u16* __restrict__ Zb, const u16* __restrict__ Wob, float* __restrict__ Out)
{
    const int bid = blockIdx.x;              // 0..511
    const int xcd = bid & 7;
    const int g = bid >> 3;                  // 0..63
    const int n_idx = g & 7;
    const int m_idx = xcd * 8 + (g >> 3);    // 0..63
    const int n0 = n_idx * BN;
    const int m0 = m_idx * BM;

    alignas(16) __shared__ u16 As[BM * BK];
    alignas(16) __shared__ u16 Bs[BN * BK];

    const int tid = threadIdx.x;
    const int lane = tid & 63;
    const int wave = tid >> 6;
    const int wm = (wave >> 1) * 64;
    const int wn = (wave & 1) * 64;
    const int l16 = lane & 15;
    const int quad = lane >> 4;
    const int sr8 = lane >> 3;
    const int cl = lane & 7;

    const f32x4 z4 = {0.f, 0.f, 0.f, 0.f};
    f32x4 acc[4][4];
#pragma unroll
    for (int i = 0; i < 4; i++)
#pragma unroll
        for (int j = 0; j < 4; j++) acc[i][j] = z4;

    for (int kt = 0; kt < DN; kt += BK) {
        __syncthreads();
#pragma unroll
        for (int it = 0; it < 4; ++it) {
            const int r = wave * 32 + it * 8 + sr8;
            const int cg = cl ^ (r & 7);
            async16(Zb + (size_t)(m0 + r) * DN + kt + cg * 8,
                    As + (wave * 32 + it * 8) * BK);
            async16(Wob + (size_t)(n0 + r) * DN + kt + cg * 8,
                    Bs + (wave * 32 + it * 8) * BK);
        }
        __syncthreads();
#pragma unroll
        for (int ks = 0; ks < BK; ks += 32) {
            bf16x8 af[4], bfr[4];
#pragma unroll
            for (int i = 0; i < 4; i++) {
                const int r = wm + i * 16 + l16;
                const int ch = ((ks >> 3) + quad) ^ (r & 7);
                af[i] = *(const bf16x8*)(As + r * BK + ch * 8);
            }
#pragma unroll
            for (int j = 0; j < 4; j++) {
                const int r = wn + j * 16 + l16;
                const int ch = ((ks >> 3) + quad) ^ (r & 7);
                bfr[j] = *(const bf16x8*)(Bs + r * BK + ch * 8);
            }
#pragma unroll
            for (int i = 0; i < 4; i++)
#pragma unroll
                for (int j = 0; j < 4; j++)
                    acc[i][j] = __builtin_amdgcn_mfma_f32_16x16x32_bf16(af[i], bfr[j], acc[i][j], 0, 0, 0);
        }
    }

#pragma unroll
    for (int i = 0; i < 4; i++)
#pragma unroll
        for (int j = 0; j < 4; j++) {
            int n = n0 + wn + j * 16 + l16;
#pragma unroll
            for (int r = 0; r < 4; r++) {
                int m = m0 + wm + i * 16 + quad * 4 + r;
                Out[(size_t)m * DM + n] = acc[i][j][r];
            }
        }
}

// ---------------- single-kernel hierarchical scan for one time chunk ----------------
// Block = (batch b, 32-neuron slice). 1024 threads = 32 time-groups x 32 neurons.
// Phase 1: thread scans its 16-step sub-chunk -> (D,S) in LDS. Prefix by tg==0 threads.
// Phase 2: re-scan with true init, emit Z. In-place state carry (block-exclusive slice).
__global__ __launch_bounds__(1024) void scan_fused(
    const u16* __restrict__ omd_a, const u16* __restrict__ sig_a,
    const u16* __restrict__ raw_a, const u16* __restrict__ modp_a,
    float* __restrict__ state_cur, const float* __restrict__ sw_logit,
    u16* __restrict__ Z, float* __restrict__ fs_out, int ci_t)
{
    __shared__ float Ds[32][32];
    __shared__ float Ss[32][32];
    __shared__ float Is[32][32];

    const int tid = threadIdx.x;
    const int nl = tid & 31;
    const int tg = tid >> 5;
    const int bx = blockIdx.x;               // BB * (DN/32) = 256 blocks
    const int nsl = bx & 127;
    const int b = bx >> 7;
    const int n = nsl * 32 + nl;

    const size_t base = ((size_t)(b * TC + tg * SCH)) * DN + n;   // chunk-local rows

    // phase 1: sub-chunk summary
    float D = 1.f, s = 0.f;
#pragma unroll
    for (int t = 0; t < SCH; t++) {
        size_t idx = base + (size_t)t * DN;
        float omd = bf2f(omd_a[idx]);
        float sg = bf2f(sig_a[idx]);
        float rw = bf2f(raw_a[idx]);
        float d = 1.f - omd;
        float u = omd * sg * tanh_fast(rw);
        D *= d;
        s = d * s + u;
    }
    Ds[tg][nl] = D;
    Ss[tg][nl] = s;
    __syncthreads();

    // prefix combine: tg==0 threads (one per neuron) walk the 32 summaries
    if (tg == 0) {
        float si = state_cur[b * DN + n];
        Is[0][nl] = si;
        for (int c = 0; c < 31; c++) {
            si = Ds[c][nl] * si + Ss[c][nl];
            Is[c + 1][nl] = si;
        }
    }
    __syncthreads();

    // phase 2: re-scan with true init, emit Z
    float s2 = Is[tg][nl];
    const float sw = 1.f / (1.f + __expf(-sw_logit[n]));
    const float osw = 1.f - sw;
    const size_t gbase = ((size_t)(b * TT + ci_t * TC + tg * SCH)) * DN + n;
#pragma unroll
    for (int t = 0; t < SCH; t++) {
        size_t li = base + (size_t)t * DN;
        float omd = bf2f(omd_a[li]);
        float sg = bf2f(sig_a[li]);
        float rw = bf2f(raw_a[li]);
        float mp = bf2f(modp_a[li]);
        float d = 1.f - omd;
        float u = omd * sg * tanh_fast(rw);
        s2 = d * s2 + u;
        float g2 = 0.5f * rw * (1.f + erf_fast(rw * 0.70710678f));  // exact gelu
        Z[gbase + (size_t)t * DN] = f2bf(mp * (osw * g2 + sw * s2));
    }
    if (tg == 31) {
        state_cur[b * DN + n] = s2;                 // carry to next chunk
        if (ci_t == NTC - 1) fs_out[b * DN + n] = s2;  // final_state output
    }
}

// ---------------- host launcher ----------------
extern "C" void kernel_launch(void* const* d_in, const int* in_sizes, int n_in,
                              void* d_out, int out_size, void* d_ws, size_t ws_size,
                              hipStream_t stream)
{
    const float* x = (const float*)d_in[0];
    const float* state = (const float*)d_in[1];
    const float* W_main = (const float*)d_in[2];
    const float* W_gate = (const float*)d_in[3];
    const float* W_mod = (const float*)d_in[4];
    const float* W_out = (const float*)d_in[5];
    const float* W_delta = (const float*)d_in[6];
    const float* b_delta = (const float*)d_in[7];
    const float* A_log = (const float*)d_in[8];
    const float* sw_logit = (const float*)d_in[9];

    float* out = (float*)d_out;                       // [B,T,Dm] fp32
    float* fs_out = out + (size_t)MR * DM;            // final_state [B,Dn]

    const size_t NM = (size_t)MR * DN;
    u16* Zb = (u16*)d_ws;                             // 67.11 MB
    u16* raw_c = Zb + NM;                             // 4 x 8.39 MB
    u16* sig_c = raw_c + CN;
    u16* modp_c = sig_c + CN;
    u16* omd_c = modp_c + CN;
    u16* W4b = omd_c + CN;                            // 33.55 MB
    u16* xb = W4b + (size_t)4 * DN * DM;              // 16.78 MB
    u16* woutb = xb + (size_t)MR * DM;                // 8.39 MB
    float* state_cur = (float*)(woutb + (size_t)DM * DN); // 32 KB
    // total = 159,416,320 B  (< 160,202,752 proven available)

    hipMemcpyAsync(state_cur, state, (size_t)BB * DN * sizeof(float),
                   hipMemcpyDeviceToDevice, stream);

    // one fused conversion launch: x + 4 projection weights + W_out
    {
        const int total4 = (MR * DM) / 4 + 5 * ((DN * DM) / 4);   // 7,340,032
        cvt6_kernel<<<total4 / 256, 256, 0, stream>>>(
            (const float4*)x, (const float4*)W_main, (const float4*)W_gate,
            (const float4*)W_mod, (const float4*)W_delta, (const float4*)W_out,
            (ushort4*)xb, (ushort4*)W4b, (ushort4*)woutb);
    }

    for (int ci = 0; ci < NTC; ci++) {
        gemm4_kernel<<<1024, 256, 0, stream>>>(xb, W4b, raw_c, sig_c, modp_c, omd_c,
                                               A_log, b_delta, ci);
        scan_fused<<<BB * (DN / 32), 1024, 0, stream>>>(omd_c, sig_c, raw_c, modp_c,
                                                        state_cur, sw_logit,
                                                        Zb, fs_out, ci);
    }

    gemm_out_kernel<<<512, 256, 0, stream>>>(Zb, woutb, out);
}